// Round 25
// baseline (1496.038 us; speedup 1.0000x reference)
//
#include <hip/hip_runtime.h>
#include <hip/hip_fp16.h>

#define S_ 128
#define Bt_ 512
#define E_ 128
#define H_ 256
#define G_ 1024    // 4*H
#define SH_ 32768  // S*H
#define SEG_ 32    // steps per segment
#define NSEG_ 4
#define MB_ 4      // batch rows per recurrence block (128 blocks)

typedef _Float16 half8 __attribute__((ext_vector_type(8)));
typedef _Float16 h2 __attribute__((ext_vector_type(2)));
typedef float f32x4 __attribute__((ext_vector_type(4)));

// f16x2 dot into f32 acc: single v_dot2_f32_f16 where available.
__device__ __forceinline__ float dot2(unsigned int w, unsigned int h, float acc) {
#if __has_builtin(__builtin_amdgcn_fdot2)
  return __builtin_amdgcn_fdot2(__builtin_bit_cast(h2, w), __builtin_bit_cast(h2, h), acc, false);
#else
  __half2 wh = __builtin_bit_cast(__half2, w);
  __half2 hx = __builtin_bit_cast(__half2, h);
  acc = fmaf(__half2float(wh.x), __half2float(hx.x), acc);
  acc = fmaf(__half2float(wh.y), __half2float(hx.y), acc);
  return acc;
#endif
}

__device__ __forceinline__ float sigm(float x) { return 1.0f / (1.0f + __expf(-x)); }
__device__ __forceinline__ float tanh_f(float x) { return 1.0f - 2.0f / (__expf(2.0f * x) + 1.0f); }

// ---------------- convert U[g][k] -> up[kp][g] = half2(U[g][2kp], U[g][2kp+1]) ----------------
__global__ void k_conv_u(const float* __restrict__ U, unsigned int* __restrict__ up) {
  int idx = blockIdx.x * 256 + threadIdx.x;  // 131072
  int kp = idx >> 10, g = idx & 1023;
  __half2 v;
  v.x = __float2half(U[g * H_ + 2 * kp]);
  v.y = __float2half(U[g * H_ + 2 * kp + 1]);
  up[idx] = __builtin_bit_cast(unsigned int, v);
}

// ---------------- convert W[g][e] f32 -> f16 ----------------
__global__ void k_conv_w(const float* __restrict__ W, __half* __restrict__ Wg) {
  int idx = blockIdx.x * 256 + threadIdx.x;  // 131072
  Wg[idx] = __float2half(W[idx]);
}

// ---------------- xg segment GEMM: xg[m][g] = x[m][:] @ Wg^T + b ----------------
__global__ __launch_bounds__(256) void k_xg(const float* __restrict__ x,
                                            const __half* __restrict__ Wg,
                                            const float* __restrict__ bias,
                                            __half* __restrict__ xg) {
  __shared__ __half As[128][72];
  __shared__ __half Bs[128][72];
  const int t = threadIdx.x;
  const int n0 = blockIdx.x * 128;
  const int m0 = blockIdx.y * 128;
  const int w = t >> 6, l = t & 63;
  const int l15 = l & 15, l4 = l >> 4;
  const int wm = (w >> 1) * 64, wn = (w & 1) * 64;
  const int r = t >> 1, hf = t & 1;

  f32x4 acc[4][4];
#pragma unroll
  for (int i = 0; i < 4; ++i)
#pragma unroll
    for (int j = 0; j < 4; ++j) acc[i][j] = (f32x4)0.0f;

#pragma unroll
  for (int kt = 0; kt < 2; ++kt) {
    {
      const float* xrow = x + (size_t)(m0 + r) * E_ + kt * 64 + hf * 32;
#pragma unroll
      for (int q = 0; q < 4; ++q) {
        float4 v0 = *(const float4*)(xrow + q * 8);
        float4 v1 = *(const float4*)(xrow + q * 8 + 4);
        __half2 p0, p1, p2, p3;
        p0.x = __float2half(v0.x); p0.y = __float2half(v0.y);
        p1.x = __float2half(v0.z); p1.y = __float2half(v0.w);
        p2.x = __float2half(v1.x); p2.y = __float2half(v1.y);
        p3.x = __float2half(v1.z); p3.y = __float2half(v1.w);
        uint4 pk;
        pk.x = __builtin_bit_cast(unsigned int, p0);
        pk.y = __builtin_bit_cast(unsigned int, p1);
        pk.z = __builtin_bit_cast(unsigned int, p2);
        pk.w = __builtin_bit_cast(unsigned int, p3);
        *(uint4*)&As[r][hf * 32 + q * 8] = pk;
      }
      const __half* brow = Wg + (size_t)(n0 + r) * E_ + kt * 64 + hf * 32;
#pragma unroll
      for (int q = 0; q < 4; ++q) {
        uint4 v = *(const uint4*)(brow + q * 8);
        *(uint4*)&Bs[r][hf * 32 + q * 8] = v;
      }
    }
    __syncthreads();
#pragma unroll
    for (int kk = 0; kk < 2; ++kk) {
      half8 af[4], bf[4];
#pragma unroll
      for (int i = 0; i < 4; ++i) af[i] = *(const half8*)&As[wm + i * 16 + l15][kk * 32 + l4 * 8];
#pragma unroll
      for (int j = 0; j < 4; ++j) bf[j] = *(const half8*)&Bs[wn + j * 16 + l15][kk * 32 + l4 * 8];
#pragma unroll
      for (int i = 0; i < 4; ++i)
#pragma unroll
        for (int j = 0; j < 4; ++j)
          acc[i][j] = __builtin_amdgcn_mfma_f32_16x16x32_f16(af[i], bf[j], acc[i][j], 0, 0, 0);
    }
    __syncthreads();
  }

#pragma unroll
  for (int j = 0; j < 4; ++j) {
    int col = n0 + wn + j * 16 + l15;
    float bv = bias[col];
#pragma unroll
    for (int i = 0; i < 4; ++i) {
      int mrow = m0 + wm + i * 16 + l4 * 4;
#pragma unroll
      for (int rg = 0; rg < 4; ++rg)
        xg[(size_t)(mrow + rg) * G_ + col] = __float2half(acc[i][j][rg] + bv);
    }
  }
}

// ---------------- URLSTM recurrence: 4 batches/block, plain register loads ----------------
// 128 blocks x 256 thr. Wave w owns gate w's 256-column slice of up; lane l owns
// units l*4..l*4+3 for 4 batch rows. Round-23 verified plain loads; round-24 lever:
// MB_=4 halves chip-wide weight traffic (64 MB/step, per-XCD floor ~1.9 us) and
// doubles compute per load (16 dot2/row) for latency cover. unroll 16 (proven).
__global__ __launch_bounds__(256, 1) void k_rec_seg(const __half* __restrict__ xg,
                                                    const unsigned int* __restrict__ up,
                                                    __half* __restrict__ hs,
                                                    float* __restrict__ c_state,
                                                    __half* __restrict__ h_state,
                                                    int s0) {
  __shared__ float gsh[4][MB_][256];   // 16 KB: gates[gate][batch][unit]
  __shared__ unsigned int hh[128][MB_]; // 2 KB: hh[kp][eb] = half2(h[eb][2kp],h[eb][2kp+1])
  const int t = threadIdx.x;
  const int w = t >> 6, l = t & 63;
  const int b0 = blockIdx.x * MB_;
  const int j = t;  // elementwise: hidden unit
  const int rbias = (blockIdx.x * 5) & 127;  // stagger U row order across blocks

  float c_reg[MB_];
  __half hcur[MB_];
#pragma unroll
  for (int eb = 0; eb < MB_; ++eb) {
    c_reg[eb] = (s0 == 0) ? 0.0f : c_state[(b0 + eb) * H_ + j];
    hcur[eb] = (s0 == 0) ? __float2half(0.0f) : h_state[(b0 + eb) * H_ + j];
    ((__half*)hh)[((j >> 1) * MB_ + eb) * 2 + (j & 1)] = hcur[eb];
  }

  const unsigned int* uw = up + w * 256 + l * 4;  // this lane's 16B column slice

  asm volatile("s_waitcnt lgkmcnt(0)" ::: "memory");
  __builtin_amdgcn_s_barrier();

  for (int sl = 0; sl < SEG_; ++sl) {
    const int s = s0 + sl;

    // ---- acc init from xg (4 batches) ----
    uint2 xv[MB_];
#pragma unroll
    for (int eb = 0; eb < MB_; ++eb)
      xv[eb] = *(const uint2*)(xg + ((size_t)sl * Bt_ + b0 + eb) * G_ + w * 256 + l * 4);
    float acc[MB_][4];
#pragma unroll
    for (int eb = 0; eb < MB_; ++eb) {
      __half2 a01 = __builtin_bit_cast(__half2, xv[eb].x);
      __half2 a23 = __builtin_bit_cast(__half2, xv[eb].y);
      acc[eb][0] = __half2float(a01.x);
      acc[eb][1] = __half2float(a01.y);
      acc[eb][2] = __half2float(a23.x);
      acc[eb][3] = __half2float(a23.y);
    }

    // ---- all 128 K-rows: plain vector loads, 16 dot2 per row, staggered order ----
#pragma unroll 16
    for (int i = 0; i < 128; ++i) {
      const int kp = (i + rbias) & 127;
      uint4 wv = *(const uint4*)(uw + (size_t)kp * G_);
      uint4 hv = *(const uint4*)&hh[kp][0];
      const unsigned int hb[4] = {hv.x, hv.y, hv.z, hv.w};
      const unsigned int wb[4] = {wv.x, wv.y, wv.z, wv.w};
#pragma unroll
      for (int eb = 0; eb < MB_; ++eb)
#pragma unroll
        for (int q = 0; q < 4; ++q)
          acc[eb][q] = dot2(wb[q], hb[eb], acc[eb][q]);
    }

    // ---- publish this wave's gate slice (4 batches) ----
#pragma unroll
    for (int eb = 0; eb < MB_; ++eb) {
      float4 fv = {acc[eb][0], acc[eb][1], acc[eb][2], acc[eb][3]};
      *(float4*)&gsh[w][eb][l * 4] = fv;
    }
    asm volatile("s_waitcnt lgkmcnt(0)" ::: "memory");
    __builtin_amdgcn_s_barrier();

    // ---- elementwise URLSTM update: thread owns unit j, 4 batches ----
#pragma unroll
    for (int eb = 0; eb < MB_; ++eb) {
      float f_ = gsh[0][eb][j];
      float r_ = gsh[1][eb][j];
      float u_ = gsh[2][eb][j];
      float o_ = gsh[3][eb][j];
      float f = sigm(f_ + 1.0f);
      float r = sigm(r_ - 1.0f);
      float g = 2.0f * r * f + (1.0f - 2.0f * r) * f * f;
      c_reg[eb] = g * c_reg[eb] + (1.0f - g) * tanh_f(u_);
      float hn = tanh_f(c_reg[eb]) * sigm(o_);
      hcur[eb] = __float2half(hn);
      ((__half*)hh)[((j >> 1) * MB_ + eb) * 2 + (j & 1)] = hcur[eb];
      hs[(size_t)(b0 + eb) * SH_ + s * H_ + j] = hcur[eb];
    }
    asm volatile("s_waitcnt lgkmcnt(0)" ::: "memory");
    __builtin_amdgcn_s_barrier();
  }

#pragma unroll
  for (int eb = 0; eb < MB_; ++eb) {
    c_state[(b0 + eb) * H_ + j] = c_reg[eb];
    h_state[(b0 + eb) * H_ + j] = hcur[eb];
  }
}

// ---------------- gemm1: part[kz] = hs_f16 @ W1^T, split-K=8, 256 thr ----------------
__global__ __launch_bounds__(256) void k_gemm1(const __half* __restrict__ hs,
                                               const float* __restrict__ W1,
                                               float* __restrict__ part) {
  __shared__ __half As[128][40];
  __shared__ __half Bs[64][40];
  const int t = threadIdx.x;
  const int n0 = blockIdx.x * 64;
  const int m0 = blockIdx.y * 128;
  const int kz = blockIdx.z;
  const int w = t >> 6, l = t & 63;
  const int l15 = l & 15, l4 = l >> 4;
  const int wm = (w >> 1) * 64;
  const int wn = (w & 1) * 32;
  const int ra = t >> 1, ca = (t & 1) * 16;
  const int rb = t >> 2, cb = (t & 3) * 8;

  f32x4 acc[4][2];
#pragma unroll
  for (int i = 0; i < 4; ++i)
#pragma unroll
    for (int j = 0; j < 2; ++j) acc[i][j] = (f32x4)0.0f;

  const size_t a_base = (size_t)(m0 + ra) * SH_ + (size_t)kz * 4096 + ca;
  const size_t b_base = (size_t)(n0 + rb) * SH_ + (size_t)kz * 4096 + cb;

  for (int kt = 0; kt < 128; ++kt) {
    uint4 av0 = *(const uint4*)(hs + a_base + kt * 32);
    uint4 av1 = *(const uint4*)(hs + a_base + kt * 32 + 8);
    float4 bv0 = *(const float4*)(W1 + b_base + kt * 32);
    float4 bv1 = *(const float4*)(W1 + b_base + kt * 32 + 4);
    __syncthreads();
    *(uint4*)&As[ra][ca] = av0;
    *(uint4*)&As[ra][ca + 8] = av1;
    {
      __half2 p0, p1, p2, p3;
      p0.x = __float2half(bv0.x); p0.y = __float2half(bv0.y);
      p1.x = __float2half(bv0.z); p1.y = __float2half(bv0.w);
      p2.x = __float2half(bv1.x); p2.y = __float2half(bv1.y);
      p3.x = __float2half(bv1.z); p3.y = __float2half(bv1.w);
      uint4 pk;
      pk.x = __builtin_bit_cast(unsigned int, p0);
      pk.y = __builtin_bit_cast(unsigned int, p1);
      pk.z = __builtin_bit_cast(unsigned int, p2);
      pk.w = __builtin_bit_cast(unsigned int, p3);
      *(uint4*)&Bs[rb][cb] = pk;
    }
    __syncthreads();
    half8 af[4], bf[2];
#pragma unroll
    for (int i = 0; i < 4; ++i) af[i] = *(const half8*)&As[wm + i * 16 + l15][l4 * 8];
#pragma unroll
    for (int j = 0; j < 2; ++j) bf[j] = *(const half8*)&Bs[wn + j * 16 + l15][l4 * 8];
#pragma unroll
    for (int i = 0; i < 4; ++i)
#pragma unroll
      for (int j = 0; j < 2; ++j)
        acc[i][j] = __builtin_amdgcn_mfma_f32_16x16x32_f16(af[i], bf[j], acc[i][j], 0, 0, 0);
  }

#pragma unroll
  for (int i = 0; i < 4; ++i)
#pragma unroll
    for (int j = 0; j < 2; ++j) {
      int col = n0 + wn + j * 16 + l15;
      int mrow = m0 + wm + i * 16 + l4 * 4;
#pragma unroll
      for (int rg = 0; rg < 4; ++rg)
        part[(size_t)kz * 524288 + (size_t)(mrow + rg) * G_ + col] = acc[i][j][rg];
    }
}

// ---------------- reduce: y = relu(sum_z part + b1), f16 out ----------------
__global__ void k_reduce(const float* __restrict__ part, const float* __restrict__ b1,
                         __half* __restrict__ y) {
  int flat = blockIdx.x * 256 + threadIdx.x;  // < 524288
  int n = flat & 1023;
  float s = b1[n];
#pragma unroll
  for (int z = 0; z < 8; ++z) s += part[(size_t)z * 524288 + flat];
  y[flat] = __float2half(fmaxf(s, 0.0f));
}

// ---------------- head: out = y @ W2^T + b2 ----------------
__global__ void k_head(const __half* __restrict__ y, const float* __restrict__ W2,
                       const float* __restrict__ b2, float* __restrict__ out) {
  const int b = blockIdx.x;
  const int lane = threadIdx.x;  // 64
  float yv[16];
#pragma unroll
  for (int i = 0; i < 16; ++i) yv[i] = __half2float(y[(size_t)b * 1024 + i * 64 + lane]);
  for (int n = 0; n < 10; ++n) {
    float p = 0.0f;
#pragma unroll
    for (int i = 0; i < 16; ++i) p += yv[i] * W2[n * 1024 + i * 64 + lane];
#pragma unroll
    for (int off = 32; off > 0; off >>= 1) p += __shfl_down(p, off);
    if (lane == 0) out[b * 10 + n] = p + b2[n];
  }
}

// ---------------- launch ----------------
// ws layout (byte offsets):
//   hs_f16   [512][32768] f16 : 0          (32 MB)
//   xg seg   [32*512][1024] f16: 33554432  (32 MB, reused per segment)
//   part     [8][512][1024] f32: 67108864  (16 MB)
//   y        [512][1024] f16  : 83886080   (1 MB)
//   up       [128][1024] u32  : 84934656   (0.5 MB)
//   Wg       [1024][128] f16  : 85458944   (0.25 MB)
//   c_state  [512][256] f32   : 85721088   (0.5 MB)
//   h_state  [512][256] f16   : 86245376   (0.25 MB)  -> total 86507520 B
extern "C" void kernel_launch(void* const* d_in, const int* in_sizes, int n_in,
                              void* d_out, int out_size, void* d_ws, size_t ws_size,
                              hipStream_t stream) {
  const float* x  = (const float*)d_in[0];
  const float* W  = (const float*)d_in[1];
  const float* U  = (const float*)d_in[2];
  const float* b  = (const float*)d_in[3];
  const float* W1 = (const float*)d_in[4];
  const float* b1 = (const float*)d_in[5];
  const float* W2 = (const float*)d_in[6];
  const float* b2 = (const float*)d_in[7];
  float* out = (float*)d_out;

  char* base = (char*)d_ws;
  __half*       hs      = (__half*)(base);
  __half*       xg      = (__half*)(base + 33554432);
  float*        part    = (float*)(base + 67108864);
  __half*       y       = (__half*)(base + 83886080);
  unsigned int* up      = (unsigned int*)(base + 84934656);
  __half*       Wg      = (__half*)(base + 85458944);
  float*        c_state = (float*)(base + 85721088);
  __half*       h_state = (__half*)(base + 86245376);

  k_conv_u<<<512, 256, 0, stream>>>(U, up);
  k_conv_w<<<512, 256, 0, stream>>>(W, Wg);

  for (int sg = 0; sg < NSEG_; ++sg) {
    const float* xseg = x + (size_t)sg * SEG_ * Bt_ * E_;
    k_xg<<<dim3(8, SEG_ * Bt_ / 128), 256, 0, stream>>>(xseg, Wg, b, xg);
    k_rec_seg<<<Bt_ / MB_, 256, 0, stream>>>(xg, up, hs, c_state, h_state, sg * SEG_);
  }

  k_gemm1<<<dim3(16, 4, 8), 256, 0, stream>>>(hs, W1, part);
  k_reduce<<<2048, 256, 0, stream>>>(part, b1, y);
  k_head<<<512, 64, 0, stream>>>(y, W2, b2, out);
}

// Round 26
// 1247.286 us; speedup vs baseline: 1.1994x; 1.1994x over previous
//
#include <hip/hip_runtime.h>
#include <hip/hip_fp16.h>

#define S_ 128
#define Bt_ 512
#define E_ 128
#define H_ 256
#define G_ 1024    // 4*H
#define SH_ 32768  // S*H
#define SEG_ 32    // steps per segment
#define NSEG_ 4

typedef _Float16 half8 __attribute__((ext_vector_type(8)));
typedef _Float16 h2 __attribute__((ext_vector_type(2)));
typedef float f32x4 __attribute__((ext_vector_type(4)));

// f16x2 dot into f32 acc: single v_dot2_f32_f16 where available.
__device__ __forceinline__ float dot2(unsigned int w, unsigned int h, float acc) {
#if __has_builtin(__builtin_amdgcn_fdot2)
  return __builtin_amdgcn_fdot2(__builtin_bit_cast(h2, w), __builtin_bit_cast(h2, h), acc, false);
#else
  __half2 wh = __builtin_bit_cast(__half2, w);
  __half2 hx = __builtin_bit_cast(__half2, h);
  acc = fmaf(__half2float(wh.x), __half2float(hx.x), acc);
  acc = fmaf(__half2float(wh.y), __half2float(hx.y), acc);
  return acc;
#endif
}

__device__ __forceinline__ float sigm(float x) { return 1.0f / (1.0f + __expf(-x)); }
__device__ __forceinline__ float tanh_f(float x) { return 1.0f - 2.0f / (__expf(2.0f * x) + 1.0f); }

// ---------------- convert U[g][k] -> up[kp][g] = half2(U[g][2kp], U[g][2kp+1]) ----------------
__global__ void k_conv_u(const float* __restrict__ U, unsigned int* __restrict__ up) {
  int idx = blockIdx.x * 256 + threadIdx.x;  // 131072
  int kp = idx >> 10, g = idx & 1023;
  __half2 v;
  v.x = __float2half(U[g * H_ + 2 * kp]);
  v.y = __float2half(U[g * H_ + 2 * kp + 1]);
  up[idx] = __builtin_bit_cast(unsigned int, v);
}

// ---------------- convert W[g][e] f32 -> f16 ----------------
__global__ void k_conv_w(const float* __restrict__ W, __half* __restrict__ Wg) {
  int idx = blockIdx.x * 256 + threadIdx.x;  // 131072
  Wg[idx] = __float2half(W[idx]);
}

// ---------------- xg segment GEMM: xg[m][g] = x[m][:] @ Wg^T + b ----------------
__global__ __launch_bounds__(256) void k_xg(const float* __restrict__ x,
                                            const __half* __restrict__ Wg,
                                            const float* __restrict__ bias,
                                            __half* __restrict__ xg) {
  __shared__ __half As[128][72];
  __shared__ __half Bs[128][72];
  const int t = threadIdx.x;
  const int n0 = blockIdx.x * 128;
  const int m0 = blockIdx.y * 128;
  const int w = t >> 6, l = t & 63;
  const int l15 = l & 15, l4 = l >> 4;
  const int wm = (w >> 1) * 64, wn = (w & 1) * 64;
  const int r = t >> 1, hf = t & 1;

  f32x4 acc[4][4];
#pragma unroll
  for (int i = 0; i < 4; ++i)
#pragma unroll
    for (int j = 0; j < 4; ++j) acc[i][j] = (f32x4)0.0f;

#pragma unroll
  for (int kt = 0; kt < 2; ++kt) {
    {
      const float* xrow = x + (size_t)(m0 + r) * E_ + kt * 64 + hf * 32;
#pragma unroll
      for (int q = 0; q < 4; ++q) {
        float4 v0 = *(const float4*)(xrow + q * 8);
        float4 v1 = *(const float4*)(xrow + q * 8 + 4);
        __half2 p0, p1, p2, p3;
        p0.x = __float2half(v0.x); p0.y = __float2half(v0.y);
        p1.x = __float2half(v0.z); p1.y = __float2half(v0.w);
        p2.x = __float2half(v1.x); p2.y = __float2half(v1.y);
        p3.x = __float2half(v1.z); p3.y = __float2half(v1.w);
        uint4 pk;
        pk.x = __builtin_bit_cast(unsigned int, p0);
        pk.y = __builtin_bit_cast(unsigned int, p1);
        pk.z = __builtin_bit_cast(unsigned int, p2);
        pk.w = __builtin_bit_cast(unsigned int, p3);
        *(uint4*)&As[r][hf * 32 + q * 8] = pk;
      }
      const __half* brow = Wg + (size_t)(n0 + r) * E_ + kt * 64 + hf * 32;
#pragma unroll
      for (int q = 0; q < 4; ++q) {
        uint4 v = *(const uint4*)(brow + q * 8);
        *(uint4*)&Bs[r][hf * 32 + q * 8] = v;
      }
    }
    __syncthreads();
#pragma unroll
    for (int kk = 0; kk < 2; ++kk) {
      half8 af[4], bf[4];
#pragma unroll
      for (int i = 0; i < 4; ++i) af[i] = *(const half8*)&As[wm + i * 16 + l15][kk * 32 + l4 * 8];
#pragma unroll
      for (int j = 0; j < 4; ++j) bf[j] = *(const half8*)&Bs[wn + j * 16 + l15][kk * 32 + l4 * 8];
#pragma unroll
      for (int i = 0; i < 4; ++i)
#pragma unroll
        for (int j = 0; j < 4; ++j)
          acc[i][j] = __builtin_amdgcn_mfma_f32_16x16x32_f16(af[i], bf[j], acc[i][j], 0, 0, 0);
    }
    __syncthreads();
  }

#pragma unroll
  for (int j = 0; j < 4; ++j) {
    int col = n0 + wn + j * 16 + l15;
    float bv = bias[col];
#pragma unroll
    for (int i = 0; i < 4; ++i) {
      int mrow = m0 + wm + i * 16 + l4 * 4;
#pragma unroll
      for (int rg = 0; rg < 4; ++rg)
        xg[(size_t)(mrow + rg) * G_ + col] = __float2half(acc[i][j][rg] + bv);
    }
  }
}

// ---------------- URLSTM recurrence: round-23 structure + asm-pipelined row loop ----------------
// 256 blocks x 256 thr (1 block/CU). Wave w owns gate w's 256-column slice; lane l
// owns units l*4..l*4+3, 2 batches. Rounds 24/25 proved hipcc sinks plain loads
// (VGPR 48, ~8 in flight); here weights+xg load via inline-asm global_load (cannot
// be sunk), 4 groups x 8 rows, issue g+3 while computing g, steady s_waitcnt
// vmcnt(24) + sched_barrier(0) (guide rule #18). In-order vmcnt retirement drains
// prior hs stores + xg at the first wait.
__global__ __launch_bounds__(256, 1) void k_rec_seg(const __half* __restrict__ xg,
                                                    const unsigned int* __restrict__ up,
                                                    __half* __restrict__ hs,
                                                    float* __restrict__ c_state,
                                                    __half* __restrict__ h_state,
                                                    int s0) {
  __shared__ float gsh[4][2][256];   // 8 KB: gates[gate][batch][unit]
  __shared__ unsigned int hh[256];   // 1 KB: hh[kp*2+eb] = half2(h[2kp],h[2kp+1])
  const int t = threadIdx.x;
  const int w = t >> 6, l = t & 63;
  const int b0 = blockIdx.x * 2;
  const int j = t;  // elementwise: hidden unit
  const int rbias = (blockIdx.x * 5) & 127;  // stagger U row order across blocks

  float c_reg[2];
  __half hcur[2];
#pragma unroll
  for (int eb = 0; eb < 2; ++eb) {
    c_reg[eb] = (s0 == 0) ? 0.0f : c_state[(b0 + eb) * H_ + j];
    hcur[eb] = (s0 == 0) ? __float2half(0.0f) : h_state[(b0 + eb) * H_ + j];
    ((__half*)hh)[((j >> 1) * 2 + eb) * 2 + (j & 1)] = hcur[eb];
  }

  const unsigned int* uw = up + w * 256 + l * 4;  // this lane's 16B column slice

  asm volatile("s_waitcnt lgkmcnt(0)" ::: "memory");
  __builtin_amdgcn_s_barrier();

  for (int sl = 0; sl < SEG_; ++sl) {
    const int s = s0 + sl;

    // ---- 1) xg loads via asm (oldest in vmcnt queue) ----
    uint2 xv[2];
#pragma unroll
    for (int eb = 0; eb < 2; ++eb) {
      const __half* xp = xg + ((size_t)sl * Bt_ + b0 + eb) * G_ + w * 256 + l * 4;
      asm volatile("global_load_dwordx2 %0, %1, off" : "=v"(xv[eb]) : "v"(xp) : "memory");
    }

    // ---- 2) prologue: issue weight groups 0..2 (24 loads) via asm ----
    uint4 buf[4][8];
#pragma unroll
    for (int pg = 0; pg < 3; ++pg)
#pragma unroll
      for (int r = 0; r < 8; ++r) {
        const int kp = ((pg * 8 + r) + rbias) & 127;
        const unsigned int* p = uw + (size_t)kp * G_;
        asm volatile("global_load_dwordx4 %0, %1, off" : "=v"(buf[pg][r]) : "v"(p) : "memory");
      }

    // ---- 3) wait for xg (allow 24 weight loads outstanding), init acc ----
    asm volatile("s_waitcnt vmcnt(24)" ::: "memory");
    __builtin_amdgcn_sched_barrier(0);
    float acc[2][4];
#pragma unroll
    for (int eb = 0; eb < 2; ++eb) {
      __half2 a01 = __builtin_bit_cast(__half2, xv[eb].x);
      __half2 a23 = __builtin_bit_cast(__half2, xv[eb].y);
      acc[eb][0] = __half2float(a01.x);
      acc[eb][1] = __half2float(a01.y);
      acc[eb][2] = __half2float(a23.x);
      acc[eb][3] = __half2float(a23.y);
    }

    // ---- 4) 16 groups x 8 rows: issue g+3, wait (counted), compute g ----
#pragma unroll
    for (int g = 0; g < 16; ++g) {
      if (g + 3 < 16) {
#pragma unroll
        for (int r = 0; r < 8; ++r) {
          const int kp = (((g + 3) * 8 + r) + rbias) & 127;
          const unsigned int* p = uw + (size_t)kp * G_;
          asm volatile("global_load_dwordx4 %0, %1, off"
                       : "=v"(buf[(g + 3) & 3][r]) : "v"(p) : "memory");
        }
      }
      if (g + 3 < 16)      asm volatile("s_waitcnt vmcnt(24)" ::: "memory");
      else if (g == 13)    asm volatile("s_waitcnt vmcnt(16)" ::: "memory");
      else if (g == 14)    asm volatile("s_waitcnt vmcnt(8)" ::: "memory");
      else                 asm volatile("s_waitcnt vmcnt(0)" ::: "memory");
      __builtin_amdgcn_sched_barrier(0);

#pragma unroll
      for (int r = 0; r < 8; ++r) {
        const int kp = ((g * 8 + r) + rbias) & 127;
        uint4 wv = buf[g & 3][r];
        uint2 hv = *(const uint2*)&hh[kp * 2];
        acc[0][0] = dot2(wv.x, hv.x, acc[0][0]);
        acc[0][1] = dot2(wv.y, hv.x, acc[0][1]);
        acc[0][2] = dot2(wv.z, hv.x, acc[0][2]);
        acc[0][3] = dot2(wv.w, hv.x, acc[0][3]);
        acc[1][0] = dot2(wv.x, hv.y, acc[1][0]);
        acc[1][1] = dot2(wv.y, hv.y, acc[1][1]);
        acc[1][2] = dot2(wv.z, hv.y, acc[1][2]);
        acc[1][3] = dot2(wv.w, hv.y, acc[1][3]);
      }
    }

    // ---- 5) publish this wave's gate slice ----
#pragma unroll
    for (int eb = 0; eb < 2; ++eb) {
      float4 fv = {acc[eb][0], acc[eb][1], acc[eb][2], acc[eb][3]};
      *(float4*)&gsh[w][eb][l * 4] = fv;
    }
    asm volatile("s_waitcnt lgkmcnt(0)" ::: "memory");
    __builtin_amdgcn_s_barrier();

    // ---- 6) elementwise URLSTM update: thread owns unit j, both batches ----
#pragma unroll
    for (int eb = 0; eb < 2; ++eb) {
      float f_ = gsh[0][eb][j];
      float r_ = gsh[1][eb][j];
      float u_ = gsh[2][eb][j];
      float o_ = gsh[3][eb][j];
      float f = sigm(f_ + 1.0f);
      float r = sigm(r_ - 1.0f);
      float g = 2.0f * r * f + (1.0f - 2.0f * r) * f * f;
      c_reg[eb] = g * c_reg[eb] + (1.0f - g) * tanh_f(u_);
      float hn = tanh_f(c_reg[eb]) * sigm(o_);
      hcur[eb] = __float2half(hn);
      ((__half*)hh)[((j >> 1) * 2 + eb) * 2 + (j & 1)] = hcur[eb];
      hs[(size_t)(b0 + eb) * SH_ + s * H_ + j] = hcur[eb];
    }
    asm volatile("s_waitcnt lgkmcnt(0)" ::: "memory");
    __builtin_amdgcn_s_barrier();
  }

#pragma unroll
  for (int eb = 0; eb < 2; ++eb) {
    c_state[(b0 + eb) * H_ + j] = c_reg[eb];
    h_state[(b0 + eb) * H_ + j] = hcur[eb];
  }
}

// ---------------- gemm1: part[kz] = hs_f16 @ W1^T, split-K=8, 256 thr ----------------
__global__ __launch_bounds__(256) void k_gemm1(const __half* __restrict__ hs,
                                               const float* __restrict__ W1,
                                               float* __restrict__ part) {
  __shared__ __half As[128][40];
  __shared__ __half Bs[64][40];
  const int t = threadIdx.x;
  const int n0 = blockIdx.x * 64;
  const int m0 = blockIdx.y * 128;
  const int kz = blockIdx.z;
  const int w = t >> 6, l = t & 63;
  const int l15 = l & 15, l4 = l >> 4;
  const int wm = (w >> 1) * 64;
  const int wn = (w & 1) * 32;
  const int ra = t >> 1, ca = (t & 1) * 16;
  const int rb = t >> 2, cb = (t & 3) * 8;

  f32x4 acc[4][2];
#pragma unroll
  for (int i = 0; i < 4; ++i)
#pragma unroll
    for (int j = 0; j < 2; ++j) acc[i][j] = (f32x4)0.0f;

  const size_t a_base = (size_t)(m0 + ra) * SH_ + (size_t)kz * 4096 + ca;
  const size_t b_base = (size_t)(n0 + rb) * SH_ + (size_t)kz * 4096 + cb;

  for (int kt = 0; kt < 128; ++kt) {
    uint4 av0 = *(const uint4*)(hs + a_base + kt * 32);
    uint4 av1 = *(const uint4*)(hs + a_base + kt * 32 + 8);
    float4 bv0 = *(const float4*)(W1 + b_base + kt * 32);
    float4 bv1 = *(const float4*)(W1 + b_base + kt * 32 + 4);
    __syncthreads();
    *(uint4*)&As[ra][ca] = av0;
    *(uint4*)&As[ra][ca + 8] = av1;
    {
      __half2 p0, p1, p2, p3;
      p0.x = __float2half(bv0.x); p0.y = __float2half(bv0.y);
      p1.x = __float2half(bv0.z); p1.y = __float2half(bv0.w);
      p2.x = __float2half(bv1.x); p2.y = __float2half(bv1.y);
      p3.x = __float2half(bv1.z); p3.y = __float2half(bv1.w);
      uint4 pk;
      pk.x = __builtin_bit_cast(unsigned int, p0);
      pk.y = __builtin_bit_cast(unsigned int, p1);
      pk.z = __builtin_bit_cast(unsigned int, p2);
      pk.w = __builtin_bit_cast(unsigned int, p3);
      *(uint4*)&Bs[rb][cb] = pk;
    }
    __syncthreads();
    half8 af[4], bf[2];
#pragma unroll
    for (int i = 0; i < 4; ++i) af[i] = *(const half8*)&As[wm + i * 16 + l15][l4 * 8];
#pragma unroll
    for (int j = 0; j < 2; ++j) bf[j] = *(const half8*)&Bs[wn + j * 16 + l15][l4 * 8];
#pragma unroll
    for (int i = 0; i < 4; ++i)
#pragma unroll
      for (int j = 0; j < 2; ++j)
        acc[i][j] = __builtin_amdgcn_mfma_f32_16x16x32_f16(af[i], bf[j], acc[i][j], 0, 0, 0);
  }

#pragma unroll
  for (int i = 0; i < 4; ++i)
#pragma unroll
    for (int j = 0; j < 2; ++j) {
      int col = n0 + wn + j * 16 + l15;
      int mrow = m0 + wm + i * 16 + l4 * 4;
#pragma unroll
      for (int rg = 0; rg < 4; ++rg)
        part[(size_t)kz * 524288 + (size_t)(mrow + rg) * G_ + col] = acc[i][j][rg];
    }
}

// ---------------- reduce: y = relu(sum_z part + b1), f16 out ----------------
__global__ void k_reduce(const float* __restrict__ part, const float* __restrict__ b1,
                         __half* __restrict__ y) {
  int flat = blockIdx.x * 256 + threadIdx.x;  // < 524288
  int n = flat & 1023;
  float s = b1[n];
#pragma unroll
  for (int z = 0; z < 8; ++z) s += part[(size_t)z * 524288 + flat];
  y[flat] = __float2half(fmaxf(s, 0.0f));
}

// ---------------- head: out = y @ W2^T + b2 ----------------
__global__ void k_head(const __half* __restrict__ y, const float* __restrict__ W2,
                       const float* __restrict__ b2, float* __restrict__ out) {
  const int b = blockIdx.x;
  const int lane = threadIdx.x;  // 64
  float yv[16];
#pragma unroll
  for (int i = 0; i < 16; ++i) yv[i] = __half2float(y[(size_t)b * 1024 + i * 64 + lane]);
  for (int n = 0; n < 10; ++n) {
    float p = 0.0f;
#pragma unroll
    for (int i = 0; i < 16; ++i) p += yv[i] * W2[n * 1024 + i * 64 + lane];
#pragma unroll
    for (int off = 32; off > 0; off >>= 1) p += __shfl_down(p, off);
    if (lane == 0) out[b * 10 + n] = p + b2[n];
  }
}

// ---------------- launch ----------------
// ws layout (byte offsets):
//   hs_f16   [512][32768] f16 : 0          (32 MB)
//   xg seg   [32*512][1024] f16: 33554432  (32 MB, reused per segment)
//   part     [8][512][1024] f32: 67108864  (16 MB)
//   y        [512][1024] f16  : 83886080   (1 MB)
//   up       [128][1024] u32  : 84934656   (0.5 MB)
//   Wg       [1024][128] f16  : 85458944   (0.25 MB)
//   c_state  [512][256] f32   : 85721088   (0.5 MB)
//   h_state  [512][256] f16   : 86245376   (0.25 MB)  -> total 86507520 B
extern "C" void kernel_launch(void* const* d_in, const int* in_sizes, int n_in,
                              void* d_out, int out_size, void* d_ws, size_t ws_size,
                              hipStream_t stream) {
  const float* x  = (const float*)d_in[0];
  const float* W  = (const float*)d_in[1];
  const float* U  = (const float*)d_in[2];
  const float* b  = (const float*)d_in[3];
  const float* W1 = (const float*)d_in[4];
  const float* b1 = (const float*)d_in[5];
  const float* W2 = (const float*)d_in[6];
  const float* b2 = (const float*)d_in[7];
  float* out = (float*)d_out;

  char* base = (char*)d_ws;
  __half*       hs      = (__half*)(base);
  __half*       xg      = (__half*)(base + 33554432);
  float*        part    = (float*)(base + 67108864);
  __half*       y       = (__half*)(base + 83886080);
  unsigned int* up      = (unsigned int*)(base + 84934656);
  __half*       Wg      = (__half*)(base + 85458944);
  float*        c_state = (float*)(base + 85721088);
  __half*       h_state = (__half*)(base + 86245376);

  k_conv_u<<<512, 256, 0, stream>>>(U, up);
  k_conv_w<<<512, 256, 0, stream>>>(W, Wg);

  for (int sg = 0; sg < NSEG_; ++sg) {
    const float* xseg = x + (size_t)sg * SEG_ * Bt_ * E_;
    k_xg<<<dim3(8, SEG_ * Bt_ / 128), 256, 0, stream>>>(xseg, Wg, b, xg);
    k_rec_seg<<<256, 256, 0, stream>>>(xg, up, hs, c_state, h_state, sg * SEG_);
  }

  k_gemm1<<<dim3(16, 4, 8), 256, 0, stream>>>(hs, W1, part);
  k_reduce<<<2048, 256, 0, stream>>>(part, b1, y);
  k_head<<<512, 64, 0, stream>>>(y, W2, b2, out);
}

// Round 27
// 940.706 us; speedup vs baseline: 1.5903x; 1.3259x over previous
//
#include <hip/hip_runtime.h>
#include <hip/hip_fp16.h>

#define S_ 128
#define Bt_ 512
#define E_ 128
#define H_ 256
#define G_ 1024    // 4*H
#define SH_ 32768  // S*H
#define SEG_ 32    // steps per segment
#define NSEG_ 4

typedef _Float16 half8 __attribute__((ext_vector_type(8)));
typedef _Float16 h2 __attribute__((ext_vector_type(2)));
typedef float f32x4 __attribute__((ext_vector_type(4)));

// f16x2 dot into f32 acc: single v_dot2_f32_f16 where available.
__device__ __forceinline__ float dot2(unsigned int w, unsigned int h, float acc) {
#if __has_builtin(__builtin_amdgcn_fdot2)
  return __builtin_amdgcn_fdot2(__builtin_bit_cast(h2, w), __builtin_bit_cast(h2, h), acc, false);
#else
  __half2 wh = __builtin_bit_cast(__half2, w);
  __half2 hx = __builtin_bit_cast(__half2, h);
  acc = fmaf(__half2float(wh.x), __half2float(hx.x), acc);
  acc = fmaf(__half2float(wh.y), __half2float(hx.y), acc);
  return acc;
#endif
}

__device__ __forceinline__ float sigm(float x) { return 1.0f / (1.0f + __expf(-x)); }
__device__ __forceinline__ float tanh_f(float x) { return 1.0f - 2.0f / (__expf(2.0f * x) + 1.0f); }

// ---------------- convert U[g][k] -> up[kp][g] = half2(U[g][2kp], U[g][2kp+1]) ----------------
__global__ void k_conv_u(const float* __restrict__ U, unsigned int* __restrict__ up) {
  int idx = blockIdx.x * 256 + threadIdx.x;  // 131072
  int kp = idx >> 10, g = idx & 1023;
  __half2 v;
  v.x = __float2half(U[g * H_ + 2 * kp]);
  v.y = __float2half(U[g * H_ + 2 * kp + 1]);
  up[idx] = __builtin_bit_cast(unsigned int, v);
}

// ---------------- convert W[g][e] f32 -> f16 ----------------
__global__ void k_conv_w(const float* __restrict__ W, __half* __restrict__ Wg) {
  int idx = blockIdx.x * 256 + threadIdx.x;  // 131072
  Wg[idx] = __float2half(W[idx]);
}

// ---------------- xg segment GEMM: xg[m][g] = x[m][:] @ Wg^T + b ----------------
__global__ __launch_bounds__(256) void k_xg(const float* __restrict__ x,
                                            const __half* __restrict__ Wg,
                                            const float* __restrict__ bias,
                                            __half* __restrict__ xg) {
  __shared__ __half As[128][72];
  __shared__ __half Bs[128][72];
  const int t = threadIdx.x;
  const int n0 = blockIdx.x * 128;
  const int m0 = blockIdx.y * 128;
  const int w = t >> 6, l = t & 63;
  const int l15 = l & 15, l4 = l >> 4;
  const int wm = (w >> 1) * 64, wn = (w & 1) * 64;
  const int r = t >> 1, hf = t & 1;

  f32x4 acc[4][4];
#pragma unroll
  for (int i = 0; i < 4; ++i)
#pragma unroll
    for (int j = 0; j < 4; ++j) acc[i][j] = (f32x4)0.0f;

#pragma unroll
  for (int kt = 0; kt < 2; ++kt) {
    {
      const float* xrow = x + (size_t)(m0 + r) * E_ + kt * 64 + hf * 32;
#pragma unroll
      for (int q = 0; q < 4; ++q) {
        float4 v0 = *(const float4*)(xrow + q * 8);
        float4 v1 = *(const float4*)(xrow + q * 8 + 4);
        __half2 p0, p1, p2, p3;
        p0.x = __float2half(v0.x); p0.y = __float2half(v0.y);
        p1.x = __float2half(v0.z); p1.y = __float2half(v0.w);
        p2.x = __float2half(v1.x); p2.y = __float2half(v1.y);
        p3.x = __float2half(v1.z); p3.y = __float2half(v1.w);
        uint4 pk;
        pk.x = __builtin_bit_cast(unsigned int, p0);
        pk.y = __builtin_bit_cast(unsigned int, p1);
        pk.z = __builtin_bit_cast(unsigned int, p2);
        pk.w = __builtin_bit_cast(unsigned int, p3);
        *(uint4*)&As[r][hf * 32 + q * 8] = pk;
      }
      const __half* brow = Wg + (size_t)(n0 + r) * E_ + kt * 64 + hf * 32;
#pragma unroll
      for (int q = 0; q < 4; ++q) {
        uint4 v = *(const uint4*)(brow + q * 8);
        *(uint4*)&Bs[r][hf * 32 + q * 8] = v;
      }
    }
    __syncthreads();
#pragma unroll
    for (int kk = 0; kk < 2; ++kk) {
      half8 af[4], bf[4];
#pragma unroll
      for (int i = 0; i < 4; ++i) af[i] = *(const half8*)&As[wm + i * 16 + l15][kk * 32 + l4 * 8];
#pragma unroll
      for (int j = 0; j < 4; ++j) bf[j] = *(const half8*)&Bs[wn + j * 16 + l15][kk * 32 + l4 * 8];
#pragma unroll
      for (int i = 0; i < 4; ++i)
#pragma unroll
        for (int j = 0; j < 4; ++j)
          acc[i][j] = __builtin_amdgcn_mfma_f32_16x16x32_f16(af[i], bf[j], acc[i][j], 0, 0, 0);
    }
    __syncthreads();
  }

#pragma unroll
  for (int j = 0; j < 4; ++j) {
    int col = n0 + wn + j * 16 + l15;
    float bv = bias[col];
#pragma unroll
    for (int i = 0; i < 4; ++i) {
      int mrow = m0 + wm + i * 16 + l4 * 4;
#pragma unroll
      for (int rg = 0; rg < 4; ++rg)
        xg[(size_t)(mrow + rg) * G_ + col] = __float2half(acc[i][j][rg] + bv);
    }
  }
}

// ---------------- URLSTM recurrence: per-wave-gate slices, plain register loads ----------------
// 256 blocks x 256 thr (1 block/CU). Wave w owns gate w's 256-column slice of up;
// lane l owns units l*4..l*4+3 (2 batches). Round-23 verified optimum: plain
// global_load_dwordx4 -> dot2, compiler-scheduled, unroll 16, block-staggered row
// order. Rounds 24 (unroll 32), 25 (MB=4), 26 (asm 3-deep pipeline) all regressed;
// this is the practical limit for same-address L2 weight broadcast (~20 TB/s agg).
__global__ __launch_bounds__(256, 1) void k_rec_seg(const __half* __restrict__ xg,
                                                    const unsigned int* __restrict__ up,
                                                    __half* __restrict__ hs,
                                                    float* __restrict__ c_state,
                                                    __half* __restrict__ h_state,
                                                    int s0) {
  __shared__ float gsh[4][2][256];   // 8 KB: gates[gate][batch][unit]
  __shared__ unsigned int hh[256];   // 1 KB: hh[kp*2+eb] = half2(h[2kp],h[2kp+1])
  const int t = threadIdx.x;
  const int w = t >> 6, l = t & 63;
  const int b0 = blockIdx.x * 2;
  const int j = t;  // elementwise: hidden unit
  const int rbias = (blockIdx.x * 5) & 127;  // stagger U row order across blocks

  float c_reg[2];
  __half hcur[2];
#pragma unroll
  for (int eb = 0; eb < 2; ++eb) {
    c_reg[eb] = (s0 == 0) ? 0.0f : c_state[(b0 + eb) * H_ + j];
    hcur[eb] = (s0 == 0) ? __float2half(0.0f) : h_state[(b0 + eb) * H_ + j];
    ((__half*)hh)[((j >> 1) * 2 + eb) * 2 + (j & 1)] = hcur[eb];
  }

  const unsigned int* uw = up + w * 256 + l * 4;  // this lane's 16B column slice

  asm volatile("s_waitcnt lgkmcnt(0)" ::: "memory");
  __builtin_amdgcn_s_barrier();

  for (int sl = 0; sl < SEG_; ++sl) {
    const int s = s0 + sl;

    // ---- acc init from xg ----
    uint2 xv[2];
#pragma unroll
    for (int eb = 0; eb < 2; ++eb)
      xv[eb] = *(const uint2*)(xg + ((size_t)sl * Bt_ + b0 + eb) * G_ + w * 256 + l * 4);
    float acc[2][4];
#pragma unroll
    for (int eb = 0; eb < 2; ++eb) {
      __half2 a01 = __builtin_bit_cast(__half2, xv[eb].x);
      __half2 a23 = __builtin_bit_cast(__half2, xv[eb].y);
      acc[eb][0] = __half2float(a01.x);
      acc[eb][1] = __half2float(a01.y);
      acc[eb][2] = __half2float(a23.x);
      acc[eb][3] = __half2float(a23.y);
    }

    // ---- all 128 K-rows: plain vector loads, compiler-scheduled, staggered order ----
#pragma unroll 16
    for (int i = 0; i < 128; ++i) {
      const int kp = (i + rbias) & 127;
      uint4 wv = *(const uint4*)(uw + (size_t)kp * G_);
      uint2 hv = *(const uint2*)&hh[kp * 2];
      acc[0][0] = dot2(wv.x, hv.x, acc[0][0]);
      acc[0][1] = dot2(wv.y, hv.x, acc[0][1]);
      acc[0][2] = dot2(wv.z, hv.x, acc[0][2]);
      acc[0][3] = dot2(wv.w, hv.x, acc[0][3]);
      acc[1][0] = dot2(wv.x, hv.y, acc[1][0]);
      acc[1][1] = dot2(wv.y, hv.y, acc[1][1]);
      acc[1][2] = dot2(wv.z, hv.y, acc[1][2]);
      acc[1][3] = dot2(wv.w, hv.y, acc[1][3]);
    }

    // ---- publish this wave's gate slice ----
#pragma unroll
    for (int eb = 0; eb < 2; ++eb) {
      float4 fv = {acc[eb][0], acc[eb][1], acc[eb][2], acc[eb][3]};
      *(float4*)&gsh[w][eb][l * 4] = fv;
    }
    asm volatile("s_waitcnt lgkmcnt(0)" ::: "memory");
    __builtin_amdgcn_s_barrier();

    // ---- elementwise URLSTM update: thread owns unit j, both batches ----
#pragma unroll
    for (int eb = 0; eb < 2; ++eb) {
      float f_ = gsh[0][eb][j];
      float r_ = gsh[1][eb][j];
      float u_ = gsh[2][eb][j];
      float o_ = gsh[3][eb][j];
      float f = sigm(f_ + 1.0f);
      float r = sigm(r_ - 1.0f);
      float g = 2.0f * r * f + (1.0f - 2.0f * r) * f * f;
      c_reg[eb] = g * c_reg[eb] + (1.0f - g) * tanh_f(u_);
      float hn = tanh_f(c_reg[eb]) * sigm(o_);
      hcur[eb] = __float2half(hn);
      ((__half*)hh)[((j >> 1) * 2 + eb) * 2 + (j & 1)] = hcur[eb];
      hs[(size_t)(b0 + eb) * SH_ + s * H_ + j] = hcur[eb];
    }
    asm volatile("s_waitcnt lgkmcnt(0)" ::: "memory");
    __builtin_amdgcn_s_barrier();
  }

#pragma unroll
  for (int eb = 0; eb < 2; ++eb) {
    c_state[(b0 + eb) * H_ + j] = c_reg[eb];
    h_state[(b0 + eb) * H_ + j] = hcur[eb];
  }
}

// ---------------- gemm1: part[kz] = hs_f16 @ W1^T, split-K=8, 256 thr ----------------
__global__ __launch_bounds__(256) void k_gemm1(const __half* __restrict__ hs,
                                               const float* __restrict__ W1,
                                               float* __restrict__ part) {
  __shared__ __half As[128][40];
  __shared__ __half Bs[64][40];
  const int t = threadIdx.x;
  const int n0 = blockIdx.x * 64;
  const int m0 = blockIdx.y * 128;
  const int kz = blockIdx.z;
  const int w = t >> 6, l = t & 63;
  const int l15 = l & 15, l4 = l >> 4;
  const int wm = (w >> 1) * 64;
  const int wn = (w & 1) * 32;
  const int ra = t >> 1, ca = (t & 1) * 16;
  const int rb = t >> 2, cb = (t & 3) * 8;

  f32x4 acc[4][2];
#pragma unroll
  for (int i = 0; i < 4; ++i)
#pragma unroll
    for (int j = 0; j < 2; ++j) acc[i][j] = (f32x4)0.0f;

  const size_t a_base = (size_t)(m0 + ra) * SH_ + (size_t)kz * 4096 + ca;
  const size_t b_base = (size_t)(n0 + rb) * SH_ + (size_t)kz * 4096 + cb;

  for (int kt = 0; kt < 128; ++kt) {
    uint4 av0 = *(const uint4*)(hs + a_base + kt * 32);
    uint4 av1 = *(const uint4*)(hs + a_base + kt * 32 + 8);
    float4 bv0 = *(const float4*)(W1 + b_base + kt * 32);
    float4 bv1 = *(const float4*)(W1 + b_base + kt * 32 + 4);
    __syncthreads();
    *(uint4*)&As[ra][ca] = av0;
    *(uint4*)&As[ra][ca + 8] = av1;
    {
      __half2 p0, p1, p2, p3;
      p0.x = __float2half(bv0.x); p0.y = __float2half(bv0.y);
      p1.x = __float2half(bv0.z); p1.y = __float2half(bv0.w);
      p2.x = __float2half(bv1.x); p2.y = __float2half(bv1.y);
      p3.x = __float2half(bv1.z); p3.y = __float2half(bv1.w);
      uint4 pk;
      pk.x = __builtin_bit_cast(unsigned int, p0);
      pk.y = __builtin_bit_cast(unsigned int, p1);
      pk.z = __builtin_bit_cast(unsigned int, p2);
      pk.w = __builtin_bit_cast(unsigned int, p3);
      *(uint4*)&Bs[rb][cb] = pk;
    }
    __syncthreads();
    half8 af[4], bf[2];
#pragma unroll
    for (int i = 0; i < 4; ++i) af[i] = *(const half8*)&As[wm + i * 16 + l15][l4 * 8];
#pragma unroll
    for (int j = 0; j < 2; ++j) bf[j] = *(const half8*)&Bs[wn + j * 16 + l15][l4 * 8];
#pragma unroll
    for (int i = 0; i < 4; ++i)
#pragma unroll
      for (int j = 0; j < 2; ++j)
        acc[i][j] = __builtin_amdgcn_mfma_f32_16x16x32_f16(af[i], bf[j], acc[i][j], 0, 0, 0);
  }

#pragma unroll
  for (int i = 0; i < 4; ++i)
#pragma unroll
    for (int j = 0; j < 2; ++j) {
      int col = n0 + wn + j * 16 + l15;
      int mrow = m0 + wm + i * 16 + l4 * 4;
#pragma unroll
      for (int rg = 0; rg < 4; ++rg)
        part[(size_t)kz * 524288 + (size_t)(mrow + rg) * G_ + col] = acc[i][j][rg];
    }
}

// ---------------- reduce: y = relu(sum_z part + b1), f16 out ----------------
__global__ void k_reduce(const float* __restrict__ part, const float* __restrict__ b1,
                         __half* __restrict__ y) {
  int flat = blockIdx.x * 256 + threadIdx.x;  // < 524288
  int n = flat & 1023;
  float s = b1[n];
#pragma unroll
  for (int z = 0; z < 8; ++z) s += part[(size_t)z * 524288 + flat];
  y[flat] = __float2half(fmaxf(s, 0.0f));
}

// ---------------- head: out = y @ W2^T + b2 ----------------
__global__ void k_head(const __half* __restrict__ y, const float* __restrict__ W2,
                       const float* __restrict__ b2, float* __restrict__ out) {
  const int b = blockIdx.x;
  const int lane = threadIdx.x;  // 64
  float yv[16];
#pragma unroll
  for (int i = 0; i < 16; ++i) yv[i] = __half2float(y[(size_t)b * 1024 + i * 64 + lane]);
  for (int n = 0; n < 10; ++n) {
    float p = 0.0f;
#pragma unroll
    for (int i = 0; i < 16; ++i) p += yv[i] * W2[n * 1024 + i * 64 + lane];
#pragma unroll
    for (int off = 32; off > 0; off >>= 1) p += __shfl_down(p, off);
    if (lane == 0) out[b * 10 + n] = p + b2[n];
  }
}

// ---------------- launch ----------------
// ws layout (byte offsets):
//   hs_f16   [512][32768] f16 : 0          (32 MB)
//   xg seg   [32*512][1024] f16: 33554432  (32 MB, reused per segment)
//   part     [8][512][1024] f32: 67108864  (16 MB)
//   y        [512][1024] f16  : 83886080   (1 MB)
//   up       [128][1024] u32  : 84934656   (0.5 MB)
//   Wg       [1024][128] f16  : 85458944   (0.25 MB)
//   c_state  [512][256] f32   : 85721088   (0.5 MB)
//   h_state  [512][256] f16   : 86245376   (0.25 MB)  -> total 86507520 B
extern "C" void kernel_launch(void* const* d_in, const int* in_sizes, int n_in,
                              void* d_out, int out_size, void* d_ws, size_t ws_size,
                              hipStream_t stream) {
  const float* x  = (const float*)d_in[0];
  const float* W  = (const float*)d_in[1];
  const float* U  = (const float*)d_in[2];
  const float* b  = (const float*)d_in[3];
  const float* W1 = (const float*)d_in[4];
  const float* b1 = (const float*)d_in[5];
  const float* W2 = (const float*)d_in[6];
  const float* b2 = (const float*)d_in[7];
  float* out = (float*)d_out;

  char* base = (char*)d_ws;
  __half*       hs      = (__half*)(base);
  __half*       xg      = (__half*)(base + 33554432);
  float*        part    = (float*)(base + 67108864);
  __half*       y       = (__half*)(base + 83886080);
  unsigned int* up      = (unsigned int*)(base + 84934656);
  __half*       Wg      = (__half*)(base + 85458944);
  float*        c_state = (float*)(base + 85721088);
  __half*       h_state = (__half*)(base + 86245376);

  k_conv_u<<<512, 256, 0, stream>>>(U, up);
  k_conv_w<<<512, 256, 0, stream>>>(W, Wg);

  for (int sg = 0; sg < NSEG_; ++sg) {
    const float* xseg = x + (size_t)sg * SEG_ * Bt_ * E_;
    k_xg<<<dim3(8, SEG_ * Bt_ / 128), 256, 0, stream>>>(xseg, Wg, b, xg);
    k_rec_seg<<<256, 256, 0, stream>>>(xg, up, hs, c_state, h_state, sg * SEG_);
  }

  k_gemm1<<<dim3(16, 4, 8), 256, 0, stream>>>(hs, W1, part);
  k_reduce<<<2048, 256, 0, stream>>>(part, b1, y);
  k_head<<<512, 64, 0, stream>>>(y, W2, b2, out);
}